// Round 1
// baseline (94.430 us; speedup 1.0000x reference)
//
#include <hip/hip_runtime.h>

#define B 4096
#define D 16
#define R 1024
#define NC 10
#define IC 170
#define NT 11          // n-tiles of 16 -> 176 padded cols
#define NP 176
#define KC 64          // k per LDS staging chunk
#define KSPLIT 4
#define RPB (R / KSPLIT)   // 256 rules per block
#define BT 16          // batch rows per block
#define BSTR 72        // padded k-stride (bf16) for Bs/As: breaks 16-way b128 bank conflict
#define GSP 192        // Gs (epilogue) padded row stride

typedef __attribute__((ext_vector_type(8))) short short8;
typedef __attribute__((ext_vector_type(4))) float f32x4;

__device__ __forceinline__ unsigned short f2bf(float f) {
    unsigned u = __float_as_uint(f);
    return (unsigned short)((u + 0x7fffu + ((u >> 16) & 1u)) >> 16);  // RNE
}

// ---------------- K0: pack rule_idx (16 dims x 2 bits). Byte q of the packed
// word is exactly the 8-bit quad-table index for dims 4q..4q+3.
__global__ void pack_rules(const int* __restrict__ rule_idx, unsigned* __restrict__ packed) {
    int r = blockIdx.x * 256 + threadIdx.x;
    unsigned bits = 0;
#pragma unroll
    for (int d = 0; d < D; ++d)
        bits |= (((unsigned)rule_idx[d * R + r]) & 3u) << (2 * d);
    packed[r] = bits;
}

// ---------------- K0b: consequents fp32 [1024][170] -> Bsw bf16 [176][1024]
// (column-major per output col: MFMA B-fragment reads become contiguous 16B)
__global__ __launch_bounds__(256) void convert_b(const float* __restrict__ cons,
                                                 unsigned short* __restrict__ Bsw) {
    int t = blockIdx.x * 256 + threadIdx.x;   // t < 176*1024
    int row = t >> 10;                        // col index 0..175
    int k   = t & 1023;
    float v = (row < IC) ? cons[(size_t)k * IC + row] : 0.0f;
    Bsw[t] = f2bf(v);
}

// ---------------- K1: firing via quad tables (4 LDS gathers/rule instead of 16)
__global__ __launch_bounds__(256) void firing_kernel(
    const float* __restrict__ x, const float* __restrict__ centers,
    const float* __restrict__ widths, const unsigned* __restrict__ packed,
    float* __restrict__ out_norm, float* __restrict__ out_xext,
    float* __restrict__ out_y)
{
    __shared__ float s_z[64];
    __shared__ float s_z2[8][16];
    __shared__ float s_z4[4 * 256];
    __shared__ float s_red[8];
    const int b = blockIdx.x, tid = threadIdx.x;

    // zero y output (runs before yhat by stream order)
    if (b < (B * NC) / 256) out_y[b * 256 + tid] = 0.0f;

    if (tid < 64) {
        int d = tid >> 2;
        float xv = x[b * D + d];
        float c = centers[tid], w = widths[tid];
        float diff = xv - c;
        s_z[tid] = 1e-9f - diff * diff / (2.0f * w * w);
    }
    if (tid < 17) out_xext[b * 17 + tid] = (tid < 16) ? x[b * D + tid] : 1.0f;
    __syncthreads();
    if (tid < 128) {  // pair tables: pair p = dims (2p, 2p+1)
        int p = tid >> 4, i = tid & 15;
        s_z2[p][i] = s_z[p * 8 + (i & 3)] + s_z[p * 8 + 4 + ((i >> 2) & 3)];
    }
    __syncthreads();
#pragma unroll
    for (int q = 0; q < 4; ++q)   // quad q = pairs (2q, 2q+1)
        s_z4[q * 256 + tid] = s_z2[2 * q][tid & 15] + s_z2[2 * q + 1][(tid >> 4) & 15];
    __syncthreads();

    float f[4], lsum = 0.0f;
#pragma unroll
    for (int j = 0; j < 4; ++j) {
        unsigned w = packed[tid + 256 * j];
        float s = s_z4[w & 255] + s_z4[256 + ((w >> 8) & 255)]
                + s_z4[512 + ((w >> 16) & 255)] + s_z4[768 + (w >> 24)];
        f[j] = __expf(s);
        lsum += f[j];
    }
#pragma unroll
    for (int off = 1; off < 64; off <<= 1) lsum += __shfl_xor(lsum, off, 64);
    const int lane = tid & 63, wid = tid >> 6;
    if (lane == 0) s_red[wid] = lsum;
    __syncthreads();
    if (tid == 0) {
        float tot = s_red[0] + s_red[1] + s_red[2] + s_red[3] + 1e-9f;
        s_red[4] = 1.0f / tot;
    }
    __syncthreads();
    const float inv = s_red[4];
#pragma unroll
    for (int j = 0; j < 4; ++j)
        out_norm[(size_t)b * R + tid + 256 * j] = f[j] * inv;
}

// ---------------- K2: MFMA GEMM. Block = 16 rows x 176 cols, K-slice of 256
// rules (KSPLIT=4). 4 waves split the 11 n-tiles 3/3/3/2. A (norm fp32) is
// converted to bf16 during LDS staging. Epilogue contracts with x_ext in-LDS
// and atomicAdds partial y (y pre-zeroed by K1).
__global__ __launch_bounds__(256, 4) void yhat_kernel(
    const float* __restrict__ norm, const unsigned short* __restrict__ Bsw,
    const float* __restrict__ x, float* __restrict__ out_y)
{
    __shared__ unsigned short Bs[NT * 16 * BSTR];   // 25344 B (reused as Gs)
    __shared__ unsigned short As[BT * BSTR];        // 2304 B
    __shared__ float xe[BT * 17];

    const int tid = threadIdx.x;
    const int mt = blockIdx.x & 255;
    const int ks = blockIdx.x >> 8;
    const int bl0 = mt * BT;
    const int r_base = ks * RPB;

    for (int t = tid; t < BT * 17; t += 256) {      // 272 > 256: strided loop!
        int bl = t / 17, i = t - bl * 17;
        xe[t] = (i < 16) ? x[(size_t)(bl0 + bl) * D + i] : 1.0f;
    }

    const int lane = tid & 63, wv = tid >> 6;
    const int m_ = lane & 15, q_ = lane >> 4;
    const int nt0 = wv * 3;
    const int ntn = (wv == 3) ? 2 : 3;

    f32x4 acc[3];
    const f32x4 zf = {0.f, 0.f, 0.f, 0.f};
    acc[0] = zf; acc[1] = zf; acc[2] = zf;

    for (int c0 = 0; c0 < RPB; c0 += KC) {
        const int kabs = r_base + c0;
        __syncthreads();
        // stage B chunk: 176 cols x 64 k (128 B each) from pre-swizzled Bsw
        for (int t = tid; t < NP * 8; t += 256) {
            int row = t >> 3, seg = t & 7;
            *(short8*)&Bs[row * BSTR + seg * 8] =
                *(const short8*)&Bsw[row * R + kabs + seg * 8];
        }
        // stage A: 16 rows x 64 k, fp32 -> bf16 (exactly 256 float4 loads)
        {
            int row = tid >> 4, c4 = tid & 15;
            float4 v = *(const float4*)&norm[(size_t)(bl0 + row) * R + kabs + c4 * 4];
            ushort4 o;
            o.x = f2bf(v.x); o.y = f2bf(v.y); o.z = f2bf(v.z); o.w = f2bf(v.w);
            *(ushort4*)&As[row * BSTR + c4 * 4] = o;
        }
        __syncthreads();
#pragma unroll
        for (int kh = 0; kh < 2; ++kh) {
            short8 a = *(const short8*)&As[m_ * BSTR + kh * 32 + q_ * 8];
#pragma unroll
            for (int j = 0; j < 3; ++j) {
                if (j < ntn) {
                    int nt = nt0 + j;
                    short8 bfrag = *(const short8*)&Bs[(nt * 16 + m_) * BSTR + kh * 32 + q_ * 8];
                    acc[j] = __builtin_amdgcn_mfma_f32_16x16x32_bf16(a, bfrag, acc[j], 0, 0, 0);
                }
            }
        }
    }

    __syncthreads();
    float* Gs = (float*)Bs;    // 16 x 192 fp32 = 12288 B, fits in Bs
#pragma unroll
    for (int j = 0; j < 3; ++j) {
        if (j < ntn) {
            int nt = nt0 + j;
#pragma unroll
            for (int r = 0; r < 4; ++r)
                Gs[(q_ * 4 + r) * GSP + nt * 16 + m_] = acc[j][r];   // C/D: col=lane&15, row=quad*4+reg
        }
    }
    __syncthreads();
    if (tid < BT * NC) {
        int bl = tid / NC, c = tid - bl * NC;
        float y = 0.0f;
#pragma unroll
        for (int i = 0; i < 17; ++i)
            y += xe[bl * 17 + i] * Gs[bl * GSP + i * NC + c];
        atomicAdd(&out_y[(size_t)(bl0 + bl) * NC + c], y);
    }
}

extern "C" void kernel_launch(void* const* d_in, const int* in_sizes, int n_in,
                              void* d_out, int out_size, void* d_ws, size_t ws_size,
                              hipStream_t stream) {
    const float* x        = (const float*)d_in[0];
    const float* centers  = (const float*)d_in[1];
    const float* widths   = (const float*)d_in[2];
    const float* cons     = (const float*)d_in[3];
    const int*   rule_idx = (const int*)d_in[4];

    float* out      = (float*)d_out;
    float* out_y    = out;                                  // (4096,10)
    float* out_norm = out + (size_t)B * NC;                 // (4096,1024)
    float* out_xext = out + (size_t)B * NC + (size_t)B * R; // (4096,17)

    unsigned* packed     = (unsigned*)d_ws;                          // 4 KB
    unsigned short* Bsw  = (unsigned short*)((char*)d_ws + 4096);    // 352 KB

    pack_rules<<<R / 256, 256, 0, stream>>>(rule_idx, packed);
    convert_b<<<(NP * R) / 256, 256, 0, stream>>>(cons, Bsw);
    firing_kernel<<<B, 256, 0, stream>>>(x, centers, widths, packed,
                                         out_norm, out_xext, out_y);
    yhat_kernel<<<(B / BT) * KSPLIT, 256, 0, stream>>>(out_norm, Bsw, x, out_y);
}

// Round 2
// 91.989 us; speedup vs baseline: 1.0265x; 1.0265x over previous
//
#include <hip/hip_runtime.h>

#define B 4096
#define D 16
#define R 1024
#define NC 10
#define IC 170
#define NT 11          // n-tiles of 16 -> 176 padded cols
#define NP 176
#define KSPLIT 8
#define RPB (R / KSPLIT)   // 128 rules (K) per block — single LDS chunk
#define BT 64          // batch rows per block
#define BSTR 136       // padded k-stride (bf16): 128+8 keeps b128 reads ~2-way
#define GSP 180        // Gs (epilogue) padded row stride (180 mod 32 = 20)

typedef __attribute__((ext_vector_type(8))) short short8;
typedef __attribute__((ext_vector_type(4))) float f32x4;

__device__ __forceinline__ unsigned short f2bf(float f) {
    unsigned u = __float_as_uint(f);
    return (unsigned short)((u + 0x7fffu + ((u >> 16) & 1u)) >> 16);  // RNE
}

// ---------------- K0: fused prep — convert_b (blocks 0..703), pack_rules
// (704..707), zero out_y (708..867). All independent, one launch.
__global__ __launch_bounds__(256) void prep_kernel(
    const float* __restrict__ cons, unsigned short* __restrict__ Bsw,
    const int* __restrict__ rule_idx, unsigned* __restrict__ packed,
    float* __restrict__ out_y)
{
    const int bid = blockIdx.x, tid = threadIdx.x;
    if (bid < 704) {
        // consequents fp32 [1024][170] -> Bsw bf16 [176][1024] (col-major per out col)
        int t = bid * 256 + tid;          // t < 176*1024
        int row = t >> 10;                // col index 0..175
        int k   = t & 1023;
        float v = (row < IC) ? cons[(size_t)k * IC + row] : 0.0f;
        Bsw[t] = f2bf(v);
    } else if (bid < 708) {
        // pack rule_idx (16 dims x 2 bits); byte q = quad-table index for dims 4q..4q+3
        int r = (bid - 704) * 256 + tid;
        unsigned bits = 0;
#pragma unroll
        for (int d = 0; d < D; ++d)
            bits |= (((unsigned)rule_idx[d * R + r]) & 3u) << (2 * d);
        packed[r] = bits;
    } else {
        out_y[(bid - 708) * 256 + tid] = 0.0f;   // stream-ordered before yhat atomics
    }
}

// ---------------- K1: firing via quad tables (4 LDS gathers/rule instead of 16)
__global__ __launch_bounds__(256) void firing_kernel(
    const float* __restrict__ x, const float* __restrict__ centers,
    const float* __restrict__ widths, const unsigned* __restrict__ packed,
    float* __restrict__ out_norm, float* __restrict__ out_xext)
{
    __shared__ float s_z[64];
    __shared__ float s_z2[8][16];
    __shared__ float s_z4[4 * 256];
    __shared__ float s_red[8];
    const int b = blockIdx.x, tid = threadIdx.x;

    if (tid < 64) {
        int d = tid >> 2;
        float xv = x[b * D + d];
        float c = centers[tid], w = widths[tid];
        float diff = xv - c;
        s_z[tid] = 1e-9f - diff * diff / (2.0f * w * w);
    }
    if (tid < 17) out_xext[b * 17 + tid] = (tid < 16) ? x[b * D + tid] : 1.0f;
    __syncthreads();
    if (tid < 128) {  // pair tables: pair p = dims (2p, 2p+1)
        int p = tid >> 4, i = tid & 15;
        s_z2[p][i] = s_z[p * 8 + (i & 3)] + s_z[p * 8 + 4 + ((i >> 2) & 3)];
    }
    __syncthreads();
#pragma unroll
    for (int q = 0; q < 4; ++q)   // quad q = pairs (2q, 2q+1)
        s_z4[q * 256 + tid] = s_z2[2 * q][tid & 15] + s_z2[2 * q + 1][(tid >> 4) & 15];
    __syncthreads();

    float f[4], lsum = 0.0f;
#pragma unroll
    for (int j = 0; j < 4; ++j) {
        unsigned w = packed[tid + 256 * j];
        float s = s_z4[w & 255] + s_z4[256 + ((w >> 8) & 255)]
                + s_z4[512 + ((w >> 16) & 255)] + s_z4[768 + (w >> 24)];
        f[j] = __expf(s);
        lsum += f[j];
    }
#pragma unroll
    for (int off = 1; off < 64; off <<= 1) lsum += __shfl_xor(lsum, off, 64);
    const int lane = tid & 63, wid = tid >> 6;
    if (lane == 0) s_red[wid] = lsum;
    __syncthreads();
    if (tid == 0) {
        float tot = s_red[0] + s_red[1] + s_red[2] + s_red[3] + 1e-9f;
        s_red[4] = 1.0f / tot;
    }
    __syncthreads();
    const float inv = s_red[4];
#pragma unroll
    for (int j = 0; j < 4; ++j)
        out_norm[(size_t)b * R + tid + 256 * j] = f[j] * inv;
}

// ---------------- K2: MFMA GEMM. Block = 64 rows x 176 cols, K-slice of 128
// rules (KSPLIT=8), single staging phase (2 barriers per block total).
// 4 waves: wave w owns n-tiles [3w, 3w+ntn) x ALL 4 m-bands -> each b-frag
// ds_read feeds 4 MFMAs (was 1 at BT=16). B-restage traffic 92MB -> 23MB.
__global__ __launch_bounds__(256, 2) void yhat_kernel(
    const float* __restrict__ norm, const unsigned short* __restrict__ Bsw,
    const float* __restrict__ x, float* __restrict__ out_y)
{
    __shared__ unsigned short Bs[NP * BSTR];    // 47872 B (reused as Gs: 46080 B)
    __shared__ unsigned short As[BT * BSTR];    // 17408 B
    __shared__ float xe[BT * 17];               // 4352 B   (total 68 KB -> 2 blocks/CU)

    const int tid = threadIdx.x;
    const int mt = blockIdx.x & 63;
    const int ks = blockIdx.x >> 6;
    const int bl0 = mt * BT;
    const int kabs = ks * RPB;

    for (int t = tid; t < BT * 17; t += 256) {
        int bl = t / 17, i = t - bl * 17;
        xe[t] = (i < 16) ? x[(size_t)(bl0 + bl) * D + i] : 1.0f;
    }
    // stage B: 176 cols x 128 k (256 B each row) from pre-swizzled Bsw
    for (int t = tid; t < NP * 16; t += 256) {
        int row = t >> 4, seg = t & 15;
        *(short8*)&Bs[row * BSTR + seg * 8] =
            *(const short8*)&Bsw[row * R + kabs + seg * 8];
    }
    // stage A: 64 rows x 128 k, fp32 -> bf16 (2048 float4 loads, 8/thread)
    for (int t = tid; t < BT * 32; t += 256) {
        int row = t >> 5, c4 = t & 31;
        float4 v = *(const float4*)&norm[(size_t)(bl0 + row) * R + kabs + c4 * 4];
        ushort4 o;
        o.x = f2bf(v.x); o.y = f2bf(v.y); o.z = f2bf(v.z); o.w = f2bf(v.w);
        *(ushort4*)&As[row * BSTR + c4 * 4] = o;
    }
    __syncthreads();

    const int lane = tid & 63, wv = tid >> 6;
    const int m_ = lane & 15, q_ = lane >> 4;
    const int nt0 = wv * 3;
    const int ntn = (wv == 3) ? 2 : 3;

    f32x4 acc[4][3];
    const f32x4 zf = {0.f, 0.f, 0.f, 0.f};
#pragma unroll
    for (int mb = 0; mb < 4; ++mb)
#pragma unroll
        for (int j = 0; j < 3; ++j) acc[mb][j] = zf;

#pragma unroll
    for (int kh = 0; kh < 4; ++kh) {
        short8 a[4];
#pragma unroll
        for (int mb = 0; mb < 4; ++mb)
            a[mb] = *(const short8*)&As[(mb * 16 + m_) * BSTR + kh * 32 + q_ * 8];
#pragma unroll
        for (int j = 0; j < 3; ++j) {
            if (j < ntn) {
                short8 bfrag = *(const short8*)&Bs[((nt0 + j) * 16 + m_) * BSTR + kh * 32 + q_ * 8];
#pragma unroll
                for (int mb = 0; mb < 4; ++mb)
                    acc[mb][j] = __builtin_amdgcn_mfma_f32_16x16x32_bf16(a[mb], bfrag, acc[mb][j], 0, 0, 0);
            }
        }
    }

    __syncthreads();
    float* Gs = (float*)Bs;    // 64 x 180 fp32 = 46080 B <= sizeof(Bs)
#pragma unroll
    for (int j = 0; j < 3; ++j) {
        if (j < ntn) {
            int nt = nt0 + j;
#pragma unroll
            for (int mb = 0; mb < 4; ++mb)
#pragma unroll
                for (int r = 0; r < 4; ++r)
                    Gs[(mb * 16 + q_ * 4 + r) * GSP + nt * 16 + m_] = acc[mb][j][r];
        }
    }
    __syncthreads();
    for (int t = tid; t < BT * NC; t += 256) {
        int bl = t / NC, c = t - bl * NC;
        float y = 0.0f;
#pragma unroll
        for (int i = 0; i < 17; ++i)
            y += xe[bl * 17 + i] * Gs[bl * GSP + i * NC + c];
        atomicAdd(&out_y[(size_t)(bl0 + bl) * NC + c], y);
    }
}

extern "C" void kernel_launch(void* const* d_in, const int* in_sizes, int n_in,
                              void* d_out, int out_size, void* d_ws, size_t ws_size,
                              hipStream_t stream) {
    const float* x        = (const float*)d_in[0];
    const float* centers  = (const float*)d_in[1];
    const float* widths   = (const float*)d_in[2];
    const float* cons     = (const float*)d_in[3];
    const int*   rule_idx = (const int*)d_in[4];

    float* out      = (float*)d_out;
    float* out_y    = out;                                  // (4096,10)
    float* out_norm = out + (size_t)B * NC;                 // (4096,1024)
    float* out_xext = out + (size_t)B * NC + (size_t)B * R; // (4096,17)

    unsigned* packed     = (unsigned*)d_ws;                          // 4 KB
    unsigned short* Bsw  = (unsigned short*)((char*)d_ws + 4096);    // 352 KB

    prep_kernel<<<868, 256, 0, stream>>>(cons, Bsw, rule_idx, packed, out_y);
    firing_kernel<<<B, 256, 0, stream>>>(x, centers, widths, packed,
                                         out_norm, out_xext);
    yhat_kernel<<<(B / BT) * KSPLIT, 256, 0, stream>>>(out_norm, Bsw, x, out_y);
}

// Round 3
// 91.456 us; speedup vs baseline: 1.0325x; 1.0058x over previous
//
#include <hip/hip_runtime.h>

#define B 4096
#define D 16
#define R 1024
#define NC 10
#define IC 170
#define NT 11          // n-tiles of 16 -> 176 padded cols
#define NP 176
#define KSPLIT 8
#define RPB (R / KSPLIT)   // 128 rules (K) per block — single LDS chunk
#define BT 64          // batch rows per block
#define BSTR 136       // padded k-stride (bf16): 128+8 keeps b128 reads ~2-way
#define GSP 180        // Gs (epilogue) padded row stride

typedef __attribute__((ext_vector_type(8))) short short8;
typedef __attribute__((ext_vector_type(4))) float f32x4;

__device__ __forceinline__ unsigned short f2bf(float f) {
    unsigned u = __float_as_uint(f);
    return (unsigned short)((u + 0x7fffu + ((u >> 16) & 1u)) >> 16);  // RNE
}

// ---------------- K0: fused prep — convert_b (blocks 0..703), pack_rules
// (704..707), zero out_y (708..867). All independent, one launch.
__global__ __launch_bounds__(256) void prep_kernel(
    const float* __restrict__ cons, unsigned short* __restrict__ Bsw,
    const int* __restrict__ rule_idx, unsigned* __restrict__ packed,
    float* __restrict__ out_y)
{
    const int bid = blockIdx.x, tid = threadIdx.x;
    if (bid < 704) {
        // consequents fp32 [1024][170] -> Bsw bf16 [176][1024] (col-major per out col)
        int t = bid * 256 + tid;          // t < 176*1024
        int row = t >> 10;                // col index 0..175
        int k   = t & 1023;
        float v = (row < IC) ? cons[(size_t)k * IC + row] : 0.0f;
        Bsw[t] = f2bf(v);
    } else if (bid < 708) {
        // pack rule_idx (16 dims x 2 bits); byte q = quad-table index for dims 4q..4q+3
        int r = (bid - 704) * 256 + tid;
        unsigned bits = 0;
#pragma unroll
        for (int d = 0; d < D; ++d)
            bits |= (((unsigned)rule_idx[d * R + r]) & 3u) << (2 * d);
        packed[r] = bits;
    } else {
        out_y[(bid - 708) * 256 + tid] = 0.0f;   // stream-ordered before yhat atomics
    }
}

// ---------------- K1: firing via quad tables. v3: 3 barriers (was 5),
// z + z2 built in-register/shuffle, uint4 packed load + float4 norm store
// (thread owns rules 4*tid..4*tid+3, fully coalesced I/O).
__global__ __launch_bounds__(256) void firing_kernel(
    const float* __restrict__ x, const float* __restrict__ centers,
    const float* __restrict__ widths, const unsigned* __restrict__ packed,
    float* __restrict__ out_norm, float* __restrict__ out_xext)
{
    __shared__ float s_z2[8][16];
    __shared__ float s_z4[4 * 256];
    __shared__ float s_red[4];
    const int b = blockIdx.x, tid = threadIdx.x;
    const int lane = tid & 63, wv = tid >> 6;

    // every wave computes z[0..63] redundantly: lane l holds z[l], l = d*4+m
    {
        int d = lane >> 2;
        float xv = x[b * D + d];
        float c = centers[lane], w = widths[lane];
        float diff = xv - c;
        float z = 1e-9f - diff * diff / (2.0f * w * w);

        if (tid < 17) out_xext[b * 17 + tid] = (tid < 16) ? x[b * D + tid] : 1.0f;

        // waves 0,1 build s_z2 (128 entries) via intra-wave shuffles of z
        if (wv < 2) {
            int p = tid >> 4, i = tid & 15;          // p in 0..7 across the 2 waves
            float za = __shfl(z, p * 8 + (i & 3), 64);
            float zb = __shfl(z, p * 8 + 4 + ((i >> 2) & 3), 64);
            s_z2[p][i] = za + zb;
        }
    }
    __syncthreads();
#pragma unroll
    for (int q = 0; q < 4; ++q)   // quad q = pairs (2q, 2q+1)
        s_z4[q * 256 + tid] = s_z2[2 * q][tid & 15] + s_z2[2 * q + 1][(tid >> 4) & 15];
    __syncthreads();

    // thread handles 4 contiguous rules: one uint4 load, one float4 store
    uint4 pw = *(const uint4*)&packed[4 * tid];
    unsigned wq[4] = {pw.x, pw.y, pw.z, pw.w};
    float f[4], lsum = 0.0f;
#pragma unroll
    for (int k = 0; k < 4; ++k) {
        unsigned wk = wq[k];
        float s = s_z4[wk & 255] + s_z4[256 + ((wk >> 8) & 255)]
                + s_z4[512 + ((wk >> 16) & 255)] + s_z4[768 + (wk >> 24)];
        f[k] = __expf(s);
        lsum += f[k];
    }
#pragma unroll
    for (int off = 1; off < 64; off <<= 1) lsum += __shfl_xor(lsum, off, 64);
    if (lane == 0) s_red[wv] = lsum;
    __syncthreads();
    const float inv = 1.0f / (s_red[0] + s_red[1] + s_red[2] + s_red[3] + 1e-9f);
    float4 o;
    o.x = f[0] * inv; o.y = f[1] * inv; o.z = f[2] * inv; o.w = f[3] * inv;
    *(float4*)&out_norm[(size_t)b * R + 4 * tid] = o;
}

// ---------------- K2: MFMA GEMM. Block = 64 rows x 176 cols, K-slice of 128
// rules (KSPLIT=8), single staging phase (2 barriers per block total).
// 4 waves: wave w owns n-tiles [3w, 3w+ntn) x ALL 4 m-bands -> each b-frag
// ds_read feeds 4 MFMAs.
__global__ __launch_bounds__(256, 2) void yhat_kernel(
    const float* __restrict__ norm, const unsigned short* __restrict__ Bsw,
    const float* __restrict__ x, float* __restrict__ out_y)
{
    __shared__ unsigned short Bs[NP * BSTR];    // 47872 B (reused as Gs: 46080 B)
    __shared__ unsigned short As[BT * BSTR];    // 17408 B
    __shared__ float xe[BT * 17];               // 4352 B   (total 68 KB -> 2 blocks/CU)

    const int tid = threadIdx.x;
    const int mt = blockIdx.x & 63;
    const int ks = blockIdx.x >> 6;
    const int bl0 = mt * BT;
    const int kabs = ks * RPB;

    for (int t = tid; t < BT * 17; t += 256) {
        int bl = t / 17, i = t - bl * 17;
        xe[t] = (i < 16) ? x[(size_t)(bl0 + bl) * D + i] : 1.0f;
    }
    // stage B: 176 cols x 128 k (256 B each row) from pre-swizzled Bsw
    for (int t = tid; t < NP * 16; t += 256) {
        int row = t >> 4, seg = t & 15;
        *(short8*)&Bs[row * BSTR + seg * 8] =
            *(const short8*)&Bsw[row * R + kabs + seg * 8];
    }
    // stage A: 64 rows x 128 k, fp32 -> bf16 (2048 float4 loads, 8/thread)
    for (int t = tid; t < BT * 32; t += 256) {
        int row = t >> 5, c4 = t & 31;
        float4 v = *(const float4*)&norm[(size_t)(bl0 + row) * R + kabs + c4 * 4];
        ushort4 o;
        o.x = f2bf(v.x); o.y = f2bf(v.y); o.z = f2bf(v.z); o.w = f2bf(v.w);
        *(ushort4*)&As[row * BSTR + c4 * 4] = o;
    }
    __syncthreads();

    const int lane = tid & 63, wv = tid >> 6;
    const int m_ = lane & 15, q_ = lane >> 4;
    const int nt0 = wv * 3;
    const int ntn = (wv == 3) ? 2 : 3;

    f32x4 acc[4][3];
    const f32x4 zf = {0.f, 0.f, 0.f, 0.f};
#pragma unroll
    for (int mb = 0; mb < 4; ++mb)
#pragma unroll
        for (int j = 0; j < 3; ++j) acc[mb][j] = zf;

#pragma unroll
    for (int kh = 0; kh < 4; ++kh) {
        short8 a[4];
#pragma unroll
        for (int mb = 0; mb < 4; ++mb)
            a[mb] = *(const short8*)&As[(mb * 16 + m_) * BSTR + kh * 32 + q_ * 8];
#pragma unroll
        for (int j = 0; j < 3; ++j) {
            if (j < ntn) {
                short8 bfrag = *(const short8*)&Bs[((nt0 + j) * 16 + m_) * BSTR + kh * 32 + q_ * 8];
#pragma unroll
                for (int mb = 0; mb < 4; ++mb)
                    acc[mb][j] = __builtin_amdgcn_mfma_f32_16x16x32_bf16(a[mb], bfrag, acc[mb][j], 0, 0, 0);
            }
        }
    }

    __syncthreads();
    float* Gs = (float*)Bs;    // 64 x 180 fp32 = 46080 B <= sizeof(Bs)
#pragma unroll
    for (int j = 0; j < 3; ++j) {
        if (j < ntn) {
            int nt = nt0 + j;
#pragma unroll
            for (int mb = 0; mb < 4; ++mb)
#pragma unroll
                for (int r = 0; r < 4; ++r)
                    Gs[(mb * 16 + q_ * 4 + r) * GSP + nt * 16 + m_] = acc[mb][j][r];
        }
    }
    __syncthreads();
    for (int t = tid; t < BT * NC; t += 256) {
        int bl = t / NC, c = t - bl * NC;
        float y = 0.0f;
#pragma unroll
        for (int i = 0; i < 17; ++i)
            y += xe[bl * 17 + i] * Gs[bl * GSP + i * NC + c];
        atomicAdd(&out_y[(size_t)(bl0 + bl) * NC + c], y);
    }
}

extern "C" void kernel_launch(void* const* d_in, const int* in_sizes, int n_in,
                              void* d_out, int out_size, void* d_ws, size_t ws_size,
                              hipStream_t stream) {
    const float* x        = (const float*)d_in[0];
    const float* centers  = (const float*)d_in[1];
    const float* widths   = (const float*)d_in[2];
    const float* cons     = (const float*)d_in[3];
    const int*   rule_idx = (const int*)d_in[4];

    float* out      = (float*)d_out;
    float* out_y    = out;                                  // (4096,10)
    float* out_norm = out + (size_t)B * NC;                 // (4096,1024)
    float* out_xext = out + (size_t)B * NC + (size_t)B * R; // (4096,17)

    unsigned* packed     = (unsigned*)d_ws;                          // 4 KB
    unsigned short* Bsw  = (unsigned short*)((char*)d_ws + 4096);    // 352 KB

    prep_kernel<<<868, 256, 0, stream>>>(cons, Bsw, rule_idx, packed, out_y);
    firing_kernel<<<B, 256, 0, stream>>>(x, centers, widths, packed,
                                         out_norm, out_xext);
    yhat_kernel<<<(B / BT) * KSPLIT, 256, 0, stream>>>(out_norm, Bsw, x, out_y);
}